// Round 1
// baseline (2107.538 us; speedup 1.0000x reference)
//
#include <hip/hip_runtime.h>
#include <math.h>
#include <stdint.h>

#define NFL 16384

struct EdgeData { int src; int ixiy; float fx; float fy; };

__device__ __forceinline__ float frelu(float x){ return x > 0.f ? x : 0.f; }

// Per-edge basis-cell precompute: disp -> polar -> bilinear cell (ix,iy) + fracs.
__global__ void prep_edges_k(const float* __restrict__ qpos,   // query (fluid) positions
                             const float* __restrict__ ppos,   // source positions
                             const int* __restrict__ tgt,
                             const int* __restrict__ src,
                             int nE, float support, float sgn,
                             EdgeData* __restrict__ out)
{
    int e = blockIdx.x * blockDim.x + threadIdx.x;
    if (e >= nE) return;
    int t = tgt[e], s = src[e];
    float dx = sgn * (ppos[2*s]   - qpos[2*t])   / support;
    float dy = sgn * (ppos[2*s+1] - qpos[2*t+1]) / support;
    dx = fminf(1.f, fmaxf(-1.f, dx));
    dy = fminf(1.f, fmaxf(-1.f, dy));
    float r  = sqrtf(dx*dx + dy*dy + 1e-12f);
    float th = atan2f(dy, dx);
    float m0 = fminf(1.f, fmaxf(-1.f, 2.f*r - 1.f));
    float m1 = fminf(1.f, fmaxf(-1.f, th * 0.3183098861837907f)); // 1/pi
    float u = (m0 + 1.f) * 3.5f;   // in [0,7]
    float v = (m1 + 1.f) * 3.5f;
    int ix = (int)u; if (ix > 6) ix = 6;
    int iy = (int)v; if (iy > 6) iy = 6;
    EdgeData ed;
    ed.src  = s;
    ed.ixiy = ix*8 + iy;           // k = ix*8 + iy (radial-major, matches basis reshape)
    ed.fx   = u - (float)ix;
    ed.fy   = v - (float)iy;
    out[e] = ed;
}

// lin = fluid_feat @ Wl0 + bl0  -> ansA[:, 0:32]
__global__ void lin0_k(const float* __restrict__ feat,
                       const float* __restrict__ Wl0,
                       const float* __restrict__ bl0,
                       float* __restrict__ ansA)
{
    int idx = blockIdx.x * blockDim.x + threadIdx.x;
    if (idx >= NFL*32) return;
    int t = idx >> 5, c = idx & 31;
    float a = bl0[c];
#pragma unroll
    for (int ci = 0; ci < 8; ++ci)
        a += feat[t*8 + ci] * Wl0[ci*32 + c];
    ansA[(size_t)t*96 + c] = a;
}

// One wave per target node. lane = cout. Edges for target t are a contiguous
// run in the sorted tgt[] array -> binary search, no atomics.
template<int CIN, int COUT, bool RELU_IN, bool HAS_DNS, bool RESID, bool FINAL>
__global__ __launch_bounds__(256)
void conv_tgt_k(const float* __restrict__ xsrc,   // source-node features (N_src x CIN)
                const float* __restrict__ xtgt,   // target-node features for dns/resid
                const EdgeData* __restrict__ ed,
                const int* __restrict__ tgt, int nE,
                const float* __restrict__ Wc, const float* __restrict__ bc,
                const float* __restrict__ Wl, const float* __restrict__ bl,
                float* __restrict__ out, int out_stride, int out_off)
{
    int t = blockIdx.x * (blockDim.x >> 6) + (threadIdx.x >> 6);
    if (t >= NFL) return;
    int lane = threadIdx.x & 63;
    int cl = lane < COUT ? lane : 0;   // clamp so inactive lanes stay in-bounds

    // edge range [eb, ee) for target t
    int lo = 0, hi = nE;
    while (lo < hi){ int mid = (lo + hi) >> 1; if (tgt[mid] <  t) lo = mid + 1; else hi = mid; }
    int eb = lo; hi = nE;
    while (lo < hi){ int mid = (lo + hi) >> 1; if (tgt[mid] <= t) lo = mid + 1; else hi = mid; }
    int ee = lo;

    float acc = 0.f;
    for (int e = eb; e < ee; ++e){
        EdgeData d = ed[e];
        int s  = __builtin_amdgcn_readfirstlane(d.src);
        int kk = __builtin_amdgcn_readfirstlane(d.ixiy);
        const float* xp = xsrc + (size_t)s * CIN;
        const float* wp = Wc + (size_t)kk * (CIN*COUT) + cl;
        float t00 = 0.f, t01 = 0.f, t10 = 0.f, t11 = 0.f;
#pragma unroll 8
        for (int ci = 0; ci < CIN; ++ci){
            float xv = xp[ci];
            if (RELU_IN) xv = frelu(xv);
            t00 += xv * wp[ci*COUT];                       // cell (ix  , iy  )
            t01 += xv * wp[ci*COUT +   CIN*COUT];          // cell (ix  , iy+1)
            t10 += xv * wp[ci*COUT + 8*CIN*COUT];          // cell (ix+1, iy  )
            t11 += xv * wp[ci*COUT + 9*CIN*COUT];          // cell (ix+1, iy+1)
        }
        float wx1 = d.fx, wy1 = d.fy;
        float wx0 = 1.f - wx1, wy0 = 1.f - wy1;
        acc += (wx0*wy0)*t00 + (wx0*wy1)*t01 + (wx1*wy0)*t10 + (wx1*wy1)*t11;
    }
    acc += bc[cl];

    if (HAS_DNS){
        const float* xt = xtgt + (size_t)t * CIN;
        float td = 0.f;
#pragma unroll 8
        for (int ci = 0; ci < CIN; ++ci)
            td += frelu(xt[ci]) * Wl[ci*COUT + cl];
        acc += td + bl[cl];
        if (RESID) acc += xt[cl];     // residual adds pre-relu input (CIN==COUT)
    }
    if (FINAL) acc *= (1.0f/128.0f);
    if (lane < COUT)
        out[(size_t)t*out_stride + out_off + lane] = acc;
}

extern "C" void kernel_launch(void* const* d_in, const int* in_sizes, int n_in,
                              void* d_out, int out_size, void* d_ws, size_t ws_size,
                              hipStream_t stream)
{
    const float* fluid_pos  = (const float*)d_in[0];
    const float* bnd_pos    = (const float*)d_in[1];
    const float* fluid_feat = (const float*)d_in[2];
    const float* bnd_feat   = (const float*)d_in[3];
    const int*   f_tgt      = (const int*)  d_in[4];
    const int*   f_src      = (const int*)  d_in[5];
    const int*   b_tgt      = (const int*)  d_in[6];
    const int*   b_src      = (const int*)  d_in[7];
    const float* Wc0 = (const float*)d_in[8];  const float* bc0 = (const float*)d_in[9];
    const float* Wc1 = (const float*)d_in[10]; const float* bc1 = (const float*)d_in[11];
    const float* Wc2 = (const float*)d_in[12]; const float* bc2 = (const float*)d_in[13];
    const float* Wc3 = (const float*)d_in[14]; const float* bc3 = (const float*)d_in[15];
    const float* Wc4 = (const float*)d_in[16]; const float* bc4 = (const float*)d_in[17];
    const float* Wl0 = (const float*)d_in[18]; const float* bl0 = (const float*)d_in[19];
    const float* Wl1 = (const float*)d_in[20]; const float* bl1 = (const float*)d_in[21];
    const float* Wl2 = (const float*)d_in[22]; const float* bl2 = (const float*)d_in[23];
    const float* Wl3 = (const float*)d_in[24]; const float* bl3 = (const float*)d_in[25];

    int nEf = in_sizes[4];
    int nEb = in_sizes[6];
    float support = (float)sqrt(16.0 / (M_PI * 16384.0));

    char* ws = (char*)d_ws;
    EdgeData* edF = (EdgeData*)ws;  ws += (size_t)nEf * sizeof(EdgeData);
    EdgeData* edB = (EdgeData*)ws;  ws += (size_t)nEb * sizeof(EdgeData);
    uintptr_t al = ((uintptr_t)ws + 255) & ~(uintptr_t)255; ws = (char*)al;
    float* ansA = (float*)ws; ws += (size_t)NFL * 96 * sizeof(float);
    float* ans1 = (float*)ws; ws += (size_t)NFL * 64 * sizeof(float);
    float* ans2 = (float*)ws; ws += (size_t)NFL * 64 * sizeof(float);

    // fdisp = (pos[tgt]-pos[src])/S  -> sgn = -1 ;  bdisp = (bnd[src]-pos[tgt])/S -> sgn = +1
    prep_edges_k<<<(nEf + 255)/256, 256, 0, stream>>>(fluid_pos, fluid_pos, f_tgt, f_src, nEf, support, -1.f, edF);
    prep_edges_k<<<(nEb + 255)/256, 256, 0, stream>>>(fluid_pos, bnd_pos,   b_tgt, b_src, nEb, support,  1.f, edB);

    lin0_k<<<(NFL*32 + 255)/256, 256, 0, stream>>>(fluid_feat, Wl0, bl0, ansA);

    dim3 cg(NFL/4);   // 4 waves (=4 targets) per 256-thread block
    // ansA[:,32:64] = fconv(fluid_feat)
    conv_tgt_k<8,32,false,false,false,false><<<cg,256,0,stream>>>(fluid_feat, nullptr, edF, f_tgt, nEf, Wc0, bc0, nullptr, nullptr, ansA, 96, 32);
    // ansA[:,64:96] = bconv(bnd_feat)
    conv_tgt_k<8,32,false,false,false,false><<<cg,256,0,stream>>>(bnd_feat,  nullptr, edB, b_tgt, nEb, Wc1, bc1, nullptr, nullptr, ansA, 96, 64);
    // block 1: ans1 = conv(relu(ansA),Wc2)+bc2 + relu(ansA)@Wl1+bl1
    conv_tgt_k<96,64,true,true,false,false><<<cg,256,0,stream>>>(ansA, ansA, edF, f_tgt, nEf, Wc2, bc2, Wl1, bl1, ans1, 64, 0);
    // block 2: ans2 = conv(relu(ans1),Wc3)+bc3 + relu(ans1)@Wl2+bl2 + ans1
    conv_tgt_k<64,64,true,true,true,false><<<cg,256,0,stream>>>(ans1, ans1, edF, f_tgt, nEf, Wc3, bc3, Wl2, bl2, ans2, 64, 0);
    // block 3: out = (conv(relu(ans2),Wc4)+bc4 + relu(ans2)@Wl3+bl3)/128
    conv_tgt_k<64,2,true,true,false,true><<<cg,256,0,stream>>>(ans2, ans2, edF, f_tgt, nEf, Wc4, bc4, Wl3, bl3, (float*)d_out, 2, 0);
}